// Round 8
// baseline (15802.847 us; speedup 1.0000x reference)
//
#include <hip/hip_runtime.h>
#include <stdint.h>

#define CRF_B 128
#define CRF_T 256
#define CRF_K 600
#define FWD_NT 640          // 10 waves
#define NWAVE 10
#define QW 152              // packed quad-words per column (600/4 = 150, +2 zero pad)
#define QREG 96             // register-resident quad-words (384 rows) — fits under 170-VGPR cap
#define QSTR (QW - QREG)    // 56 streamed quad-words (216 rows + pad)
#define ESC 60.0f           // E int8 scale: byte = rn(60*exp(trans)) <= 127 for trans <= 0.75
#define INV7620 (1.0f/7620.0f)  // 1/(127*60)

#if __has_builtin(__builtin_amdgcn_sdot4)
#define DOT4(a,b,c) __builtin_amdgcn_sdot4((int)(a),(int)(b),(int)(c),false)
#else
__device__ __forceinline__ int DOT4(uint32_t a, uint32_t b, int c) {
    c += (int)(int8_t)(a)       * (int)(int8_t)(b);
    c += (int)(int8_t)(a >> 8)  * (int)(int8_t)(b >> 8);
    c += (int)(int8_t)(a >> 16) * (int)(int8_t)(b >> 16);
    c += (int)(int8_t)(a >> 24) * (int)(int8_t)(b >> 24);
    return c;
}
#endif

// order-preserving float<->uint for atomicMax-based reductions
__device__ __forceinline__ uint32_t fmono(float x) {
    uint32_t k = __float_as_uint(x);
    return (k & 0x80000000u) ? ~k : (k | 0x80000000u);
}
__device__ __forceinline__ float funmono(uint32_t k) {
    return __uint_as_float((k & 0x80000000u) ? (k ^ 0x80000000u) : ~k);
}

// ---------------- prepE: EqT[q][j] word = int8x4 of rn(ESC*exp(trans[4q+k][j])) ----------------
__global__ __launch_bounds__(256) void prepE_kernel(const float* __restrict__ trans,
                                                    uint32_t* __restrict__ EqT)
{
    int idx = blockIdx.x * 256 + threadIdx.x;       // q*600 + j
    if (idx < QW * CRF_K) {
        int q = idx / CRF_K, j = idx % CRF_K;
        uint32_t w = 0;
        #pragma unroll
        for (int k = 0; k < 4; ++k) {
            int i = 4 * q + k;
            int b = 0;
            if (i < CRF_K) {
                b = __float2int_rn(ESC * __expf(trans[i * CRF_K + j]));
                b = min(127, max(0, b));
            }
            w |= ((uint32_t)(b & 0xff)) << (8 * k);
        }
        EqT[idx] = w;
    }
}

// ---------------- prep2: per-row max/min of trans (viterbi pruning bounds) ----------------
__global__ __launch_bounds__(64) void prep2_kernel(const float* __restrict__ trans,
                                                   float* __restrict__ rowmax,
                                                   float* __restrict__ rowmin)
{
    int r = blockIdx.x;
    int lane = threadIdx.x;
    float mx = -INFINITY, mn = INFINITY;
    for (int j = lane; j < CRF_K; j += 64) {
        float v = trans[r * CRF_K + j];
        mx = fmaxf(mx, v);
        mn = fminf(mn, v);
    }
    for (int o = 32; o; o >>= 1) {
        mx = fmaxf(mx, __shfl_down(mx, o));
        mn = fminf(mn, __shfl_down(mn, o));
    }
    if (lane == 0) { rowmax[r] = mx; rowmin[r] = mn; }
}

// ---------------- gold-path score: unary + binary ----------------
__global__ __launch_bounds__(64) void score_kernel(const float* __restrict__ pot,
                                                   const float* __restrict__ trans,
                                                   const int* __restrict__ tags,
                                                   const int* __restrict__ seq_len,
                                                   float* __restrict__ scoreArr)
{
    int b = blockIdx.x;
    int lane = threadIdx.x;
    int L = seq_len[b];
    float s = 0.f;
    for (int t = lane; t < CRF_T; t += 64) {
        if (t < L) {
            int tg = tags[b * CRF_T + t];
            s += pot[((size_t)b * CRF_T + t) * CRF_K + tg];
            if (t >= 1) {
                int tp = tags[b * CRF_T + t - 1];
                s += trans[tp * CRF_K + tg];
            }
        }
    }
    for (int o = 32; o; o >>= 1) s += __shfl_down(s, o);
    if (lane == 0) scoreArr[b] = s;
}

// ---------------- fused forward ----------------
// blocks 0..127   : Viterbi, 1 row/block, exact pruned max-plus (bit-exact f32), 2 barriers/step
// blocks 128..191 : lognorm, 2 rows/block, int8 E register-resident + sdot4, 2 barriers/step
// __launch_bounds__(640,3): 10-wave block -> 3 waves on 2 SIMDs -> VGPR cap 170 (prevents
// the round-7 spill of Ereg[] to scratch; VGPR_Count must read ~150, not 84).
__global__ __launch_bounds__(FWD_NT, 3) void fwd_kernel(
    const float* __restrict__ pot,
    const float* __restrict__ trans,
    const uint32_t* __restrict__ EqT,
    const float* __restrict__ rowmax,
    const float* __restrict__ rowmin,
    const int* __restrict__ seq_len,
    uint16_t* __restrict__ bp,
    float* __restrict__ lognormArr,
    int* __restrict__ lastArr)
{
    extern __shared__ char dynpad[];
    const int bid = blockIdx.x;
    const int tid = threadIdx.x;
    const int lane = tid & 63, wid = tid >> 6;
    const bool act = tid < CRF_K;

    __shared__ __align__(16) float sAv[2][CRF_K];        // viterbi alpha dbuf
    __shared__ int sCand[FWD_NT];                        // per-wave candidate lists
    __shared__ int sRedI[NWAVE];
    __shared__ __align__(16) uint32_t sAq[2][2][QW];     // lognorm int8 alpha dbuf [buf][row][qword]
    __shared__ float sRedA[NWAVE], sRedB[NWAVE];
    __shared__ unsigned vSlot[2];                        // viterbi LB slots (parity)
    __shared__ unsigned lSlot[2][2];                     // lognorm max slots [row][parity]
    __shared__ float sB0f, sB1f;
    __shared__ int sRedC[NWAVE];

    if (bid < CRF_B) {
        // ================= Viterbi role =================
        const int b = bid;
        const int L = seq_len[b];
        if (L < 0) ((volatile char*)dynpad)[0] = 1;      // keep dynpad allocated (never true)
        const float* pb = pot + (size_t)b * CRF_T * CRF_K;
        float rmx = act ? rowmax[tid] : 0.f;
        float rmn = act ? rowmin[tid] : 0.f;
        if (act) sAv[0][tid] = pb[tid];
        if (tid == 0) { vSlot[0] = 0u; vSlot[1] = 0u; }
        int cur = 0;
        __syncthreads();

        for (int t = 1; t < L; ++t) {
            float a_own = act ? sAv[cur][tid] : -INFINITY;
            // LB = max_i (alpha_i + rowmin_i) via wave-shfl + LDS atomicMax (monotone key)
            float li = act ? a_own + rmn : -INFINITY;
            for (int o = 32; o; o >>= 1) li = fmaxf(li, __shfl_down(li, o));
            if (lane == 0) atomicMax(&vSlot[t & 1], fmono(li));
            __syncthreads();                             // B1
            const float LB = funmono(vSlot[t & 1]);
            if (tid == 0) vSlot[(t + 1) & 1] = 0u;       // reset other parity (ordered by B2)
            // candidates: alpha_i + rowmax_i >= LB  (provable superset of winners incl. ties)
            bool flag = act && (a_own + rmx >= LB);
            uint64_t mask = __ballot(flag);
            if (flag) sCand[(wid << 6) + __popcll(mask & ((1ull << lane) - 1ull))] = tid;
            if (lane == 0) sRedI[wid] = __popcll(mask);
            __syncthreads();                             // B2
            float emitv = act ? pb[(size_t)t * CRF_K + tid] : 0.f;
            if (act) {
                float v = -INFINITY; int ix = 0;
                #pragma unroll 2
                for (int w = 0; w < NWAVE; ++w) {
                    const int cw = sRedI[w];
                    const int base = w << 6;
                    for (int k0 = 0; k0 < cw; k0 += 4) {
                        #pragma unroll
                        for (int u = 0; u < 4; ++u) {
                            int kk = k0 + u;
                            int i = sCand[base + ((kk < cw) ? kk : 0)];  // dup-pad: earlier i, strict > no-op
                            float cnd = sAv[cur][i] + trans[i * CRF_K + tid];
                            if (cnd > v) { v = cnd; ix = i; }            // ascending i -> first-max
                        }
                    }
                }
                bp[((size_t)b * (CRF_T - 1) + (t - 1)) * CRF_K + tid] = (uint16_t)ix;
                sAv[cur ^ 1][tid] = v + emitv;
            }
            cur ^= 1;
        }

        // finalize: last = argmax_j alpha (first-max tie-break)
        float mv = act ? sAv[cur][tid] : -INFINITY;
        float y = mv;
        for (int o = 32; o; o >>= 1) y = fmaxf(y, __shfl_down(y, o));
        if (lane == 0) sRedA[wid] = y;
        __syncthreads();
        if (tid == 0) { float m = sRedA[0]; for (int w = 1; w < NWAVE; ++w) m = fmaxf(m, sRedA[w]); sB0f = m; }
        __syncthreads();
        float vmax = sB0f;
        int cand = (act && mv == vmax) ? tid : 0x7fffffff;
        for (int o = 32; o; o >>= 1) cand = min(cand, __shfl_down(cand, o));
        if (lane == 0) sRedC[wid] = cand;
        __syncthreads();
        if (tid == 0) {
            int mi = sRedC[0];
            for (int w = 1; w < NWAVE; ++w) mi = min(mi, sRedC[w]);
            lastArr[b] = mi;
        }
    } else {
        // ================= lognorm role (NB=2, int8 E in registers) =================
        const int q = bid - CRF_B;
        const int b0 = 2 * q, b1 = b0 + 1;
        const int L0 = seq_len[b0], L1 = seq_len[b1];
        const int Tmax = max(L0, L1);
        if (Tmax < 0) ((volatile char*)dynpad)[0] = 1;
        const float* pb0 = pot + (size_t)b0 * CRF_T * CRF_K;
        const float* pb1 = pot + (size_t)b1 * CRF_T * CRF_K;

        // E prologue: QREG register-resident words for this thread's column (static indices)
        uint32_t Ereg[QREG];
        if (act) {
            #pragma unroll
            for (int c = 0; c < QREG; ++c) Ereg[c] = EqT[c * CRF_K + tid];
        }

        // init: m0 = max p0 per row; na = exp(p0 - m0) (max == 1 exactly)
        float p00 = act ? pb0[tid] : -INFINITY;
        float p01 = act ? pb1[tid] : -INFINITY;
        {
            float y0 = p00, y1 = p01;
            for (int o = 32; o; o >>= 1) { y0 = fmaxf(y0, __shfl_down(y0, o)); y1 = fmaxf(y1, __shfl_down(y1, o)); }
            if (lane == 0) { sRedA[wid] = y0; sRedB[wid] = y1; }
            __syncthreads();
            if (tid == 0) {
                float m0 = sRedA[0], m1 = sRedB[0];
                for (int w = 1; w < NWAVE; ++w) { m0 = fmaxf(m0, sRedA[w]); m1 = fmaxf(m1, sRedB[w]); }
                sB0f = m0; sB1f = m1;
            }
            __syncthreads();
        }
        float ls0 = sB0f, ls1 = sB1f;           // per-thread copies, kept identical
        float lsf0 = ls0, lsf1 = ls1;
        float afin0 = 0.f, afin1 = 0.f;
        if (act) {
            float na0 = __expf(p00 - sB0f);
            float na1 = __expf(p01 - sB1f);
            uint8_t* d0 = (uint8_t*)&sAq[0][0][0];
            uint8_t* d1 = (uint8_t*)&sAq[0][1][0];
            d0[tid] = (uint8_t)__float2int_rn(127.0f * na0);   // max na == 1 exactly
            d1[tid] = (uint8_t)__float2int_rn(127.0f * na1);
        }
        if (tid < 8) {   // zero pad bytes (qwords 150,151) of both rows, buf 0
            ((uint8_t*)&sAq[0][0][150])[tid & 7] = 0;
            ((uint8_t*)&sAq[0][1][150])[tid & 7] = 0;
        }
        if (tid >= 632) {  // zero pad of buf 1 (written once; frozen-copy preserves)
            ((uint8_t*)&sAq[1][0][150])[tid - 632] = 0;
            ((uint8_t*)&sAq[1][1][150])[tid - 632] = 0;
        }
        if (tid == 0) { lSlot[0][0] = 0u; lSlot[0][1] = 0u; lSlot[1][0] = 0u; lSlot[1][1] = 0u; }
        int cur = 0;
        __syncthreads();

        for (int t = 1; t < Tmax; ++t) {
            const bool lv0 = t < L0, lv1 = t < L1;
            float na0v = 0.f, na1v = 0.f;
            if (act) {
                int S0 = 0, S1 = 0;
                #pragma unroll
                for (int c = 0; c < QREG / 4; ++c) {          // 24 chunks, E from registers
                    uint4 a0 = *(const uint4*)&sAq[cur][0][4 * c];
                    uint4 a1 = *(const uint4*)&sAq[cur][1][4 * c];
                    S0 = DOT4(a0.x, Ereg[4 * c + 0], S0); S0 = DOT4(a0.y, Ereg[4 * c + 1], S0);
                    S0 = DOT4(a0.z, Ereg[4 * c + 2], S0); S0 = DOT4(a0.w, Ereg[4 * c + 3], S0);
                    S1 = DOT4(a1.x, Ereg[4 * c + 0], S1); S1 = DOT4(a1.y, Ereg[4 * c + 1], S1);
                    S1 = DOT4(a1.z, Ereg[4 * c + 2], S1); S1 = DOT4(a1.w, Ereg[4 * c + 3], S1);
                }
                const uint32_t* ep = EqT + (size_t)QREG * CRF_K + tid;
                #pragma unroll
                for (int s = 0; s < QSTR / 4; ++s) {          // 14 chunks, E streamed from L2
                    uint32_t e0 = ep[(4 * s + 0) * CRF_K];
                    uint32_t e1 = ep[(4 * s + 1) * CRF_K];
                    uint32_t e2 = ep[(4 * s + 2) * CRF_K];
                    uint32_t e3 = ep[(4 * s + 3) * CRF_K];
                    uint4 a0 = *(const uint4*)&sAq[cur][0][QREG + 4 * s];
                    uint4 a1 = *(const uint4*)&sAq[cur][1][QREG + 4 * s];
                    S0 = DOT4(a0.x, e0, S0); S0 = DOT4(a0.y, e1, S0);
                    S0 = DOT4(a0.z, e2, S0); S0 = DOT4(a0.w, e3, S0);
                    S1 = DOT4(a1.x, e0, S1); S1 = DOT4(a1.y, e1, S1);
                    S1 = DOT4(a1.z, e2, S1); S1 = DOT4(a1.w, e3, S1);
                }
                if (lv0) na0v = (float)S0 * INV7620 * __expf(pb0[(size_t)t * CRF_K + tid]);
                if (lv1) na1v = (float)S1 * INV7620 * __expf(pb1[(size_t)t * CRF_K + tid]);
                if (t == L0 - 1) { afin0 = na0v; lsf0 = ls0; }
                if (t == L1 - 1) { afin1 = na1v; lsf1 = ls1; }
            }
            // block max per row: wave shfl + LDS atomicMax (na >= 0 -> raw float bits monotone)
            float m0r = na0v, m1r = na1v;
            for (int o = 32; o; o >>= 1) { m0r = fmaxf(m0r, __shfl_down(m0r, o)); m1r = fmaxf(m1r, __shfl_down(m1r, o)); }
            if (lane == 0) {
                atomicMax(&lSlot[0][t & 1], __float_as_uint(m0r));
                atomicMax(&lSlot[1][t & 1], __float_as_uint(m1r));
            }
            __syncthreads();                                  // B1
            float m0 = __uint_as_float(lSlot[0][t & 1]);
            float m1 = __uint_as_float(lSlot[1][t & 1]);
            if (tid == 0) { lSlot[0][(t + 1) & 1] = 0u; lSlot[1][(t + 1) & 1] = 0u; }
            if (act) {
                uint8_t* d0 = (uint8_t*)&sAq[cur ^ 1][0][0];
                uint8_t* d1 = (uint8_t*)&sAq[cur ^ 1][1][0];
                const uint8_t* s0 = (const uint8_t*)&sAq[cur][0][0];
                const uint8_t* s1 = (const uint8_t*)&sAq[cur][1][0];
                if (lv0) { ls0 += __logf(m0); d0[tid] = (uint8_t)__float2int_rn(na0v * (127.0f / m0)); }
                else     { d0[tid] = s0[tid]; }
                if (lv1) { ls1 += __logf(m1); d1[tid] = (uint8_t)__float2int_rn(na1v * (127.0f / m1)); }
                else     { d1[tid] = s1[tid]; }
            }
            __syncthreads();                                  // B2
            cur ^= 1;
        }

        // finalize: lognorm_p = lsf_p + log(sum_j afin_p)
        float a0s = afin0, a1s = afin1;
        for (int o = 32; o; o >>= 1) { a0s += __shfl_down(a0s, o); a1s += __shfl_down(a1s, o); }
        if (lane == 0) { sRedA[wid] = a0s; sRedB[wid] = a1s; }
        __syncthreads();
        if (tid == 0) {
            float S0 = 0.f, S1 = 0.f;
            for (int w = 0; w < NWAVE; ++w) { S0 += sRedA[w]; S1 += sRedB[w]; }
            lognormArr[b0] = lsf0 + __logf(S0);
            lognormArr[b1] = lsf1 + __logf(S1);
        }
    }
}

// ---------------- backtrace ----------------
__global__ __launch_bounds__(64) void backtrace_kernel(const uint16_t* __restrict__ bp,
                                                       const int* __restrict__ seq_len,
                                                       const int* __restrict__ lastArr,
                                                       float* __restrict__ out)
{
    int r = blockIdx.x * 64 + threadIdx.x;
    if (r >= CRF_B) return;
    int L = seq_len[r];
    float* o = out + 1 + (size_t)r * CRF_T;
    int tag = lastArr[r];
    for (int t = CRF_T - 1; t >= L; --t) o[t] = 0.f;
    o[L - 1] = (float)tag;
    for (int t = L - 2; t >= 0; --t) {
        tag = bp[((size_t)r * (CRF_T - 1) + t) * CRF_K + tag];
        o[t] = (float)tag;
    }
}

// ---------------- loss = -mean(score - lognorm) ----------------
__global__ __launch_bounds__(128) void loss_kernel(const float* __restrict__ scoreArr,
                                                   const float* __restrict__ lognormArr,
                                                   float* __restrict__ out)
{
    int tid = threadIdx.x;
    float x = scoreArr[tid] - lognormArr[tid];
    for (int o = 32; o; o >>= 1) x += __shfl_down(x, o);
    __shared__ float r2[2];
    if ((tid & 63) == 0) r2[tid >> 6] = x;
    __syncthreads();
    if (tid == 0) out[0] = -(r2[0] + r2[1]) / (float)CRF_B;
}

extern "C" void kernel_launch(void* const* d_in, const int* in_sizes, int n_in,
                              void* d_out, int out_size, void* d_ws, size_t ws_size,
                              hipStream_t stream)
{
    const float* pot     = (const float*)d_in[0];
    const float* trans   = (const float*)d_in[1];
    const int*   tags    = (const int*)d_in[2];
    const int*   seq_len = (const int*)d_in[3];
    float* out = (float*)d_out;

    char* ws = (char*)d_ws;
    const size_t bpBytes  = (size_t)CRF_B * (CRF_T - 1) * CRF_K * 2;    // 39,168,000
    const size_t eqBytes  = (size_t)QW * CRF_K * 4;                     //    364,800
    uint16_t* bp     = (uint16_t*)ws;
    uint32_t* EqT    = (uint32_t*)(ws + bpBytes);
    float*    rowmax = (float*)(ws + bpBytes + eqBytes);
    float*    rowmin = rowmax + CRF_K;
    float* scoreArr   = rowmin + CRF_K;
    float* lognormArr = scoreArr + CRF_B;
    int*   lastArr    = (int*)(lognormArr + CRF_B);

    prepE_kernel<<<(QW * CRF_K + 255) / 256, 256, 0, stream>>>(trans, EqT);
    prep2_kernel<<<CRF_K, 64, 0, stream>>>(trans, rowmax, rowmin);
    score_kernel<<<CRF_B, 64, 0, stream>>>(pot, trans, tags, seq_len, scoreArr);
    fwd_kernel<<<CRF_B + CRF_B / 2, FWD_NT, 102400, stream>>>(pot, trans, EqT, rowmax, rowmin,
                                                              seq_len, bp, lognormArr, lastArr);
    backtrace_kernel<<<(CRF_B + 63) / 64, 64, 0, stream>>>(bp, seq_len, lastArr, out);
    loss_kernel<<<1, 128, 0, stream>>>(scoreArr, lognormArr, out);
}

// Round 9
// 6437.810 us; speedup vs baseline: 2.4547x; 2.4547x over previous
//
#include <hip/hip_runtime.h>
#include <stdint.h>

#define CRF_B 128
#define CRF_T 256
#define CRF_K 600
#define FWD_NT 640          // 10 waves
#define NWAVE 10
#define QW 152              // packed quad-words per column (600/4 = 150, +2 zero pad)
#define QREG 96             // qwords held in 24 named uint4 registers (384 rows)
#define QSTR (QW - QREG)    // 56 qwords held in dynamic LDS (216 rows + pad)
#define ESC 60.0f           // E int8 scale: byte = rn(60*exp(trans)) <= 127 for trans <= 0.75
#define INV7620 (1.0f/7620.0f)  // 1/(127*60)

#if __has_builtin(__builtin_amdgcn_sdot4)
#define DOT4(a,b,c) __builtin_amdgcn_sdot4((int)(a),(int)(b),(int)(c),false)
#else
__device__ __forceinline__ int DOT4(uint32_t a, uint32_t b, int c) {
    c += (int)(int8_t)(a)       * (int)(int8_t)(b);
    c += (int)(int8_t)(a >> 8)  * (int)(int8_t)(b >> 8);
    c += (int)(int8_t)(a >> 16) * (int)(int8_t)(b >> 16);
    c += (int)(int8_t)(a >> 24) * (int)(int8_t)(b >> 24);
    return c;
}
#endif

// order-preserving float<->uint for atomicMax-based reductions
__device__ __forceinline__ uint32_t fmono(float x) {
    uint32_t k = __float_as_uint(x);
    return (k & 0x80000000u) ? ~k : (k | 0x80000000u);
}
__device__ __forceinline__ float funmono(uint32_t k) {
    return __uint_as_float((k & 0x80000000u) ? (k ^ 0x80000000u) : ~k);
}

// ---------------- prepE: EqT[q][j] word = int8x4 of rn(ESC*exp(trans[4q+k][j])) ----------------
__global__ __launch_bounds__(256) void prepE_kernel(const float* __restrict__ trans,
                                                    uint32_t* __restrict__ EqT)
{
    int idx = blockIdx.x * 256 + threadIdx.x;       // q*600 + j
    if (idx < QW * CRF_K) {
        int q = idx / CRF_K, j = idx % CRF_K;
        uint32_t w = 0;
        #pragma unroll
        for (int k = 0; k < 4; ++k) {
            int i = 4 * q + k;
            int b = 0;
            if (i < CRF_K) {
                b = __float2int_rn(ESC * __expf(trans[i * CRF_K + j]));
                b = min(127, max(0, b));
            }
            w |= ((uint32_t)(b & 0xff)) << (8 * k);
        }
        EqT[idx] = w;
    }
}

// ---------------- prep2: per-row max/min of trans (viterbi pruning bounds) ----------------
__global__ __launch_bounds__(64) void prep2_kernel(const float* __restrict__ trans,
                                                   float* __restrict__ rowmax,
                                                   float* __restrict__ rowmin)
{
    int r = blockIdx.x;
    int lane = threadIdx.x;
    float mx = -INFINITY, mn = INFINITY;
    for (int j = lane; j < CRF_K; j += 64) {
        float v = trans[r * CRF_K + j];
        mx = fmaxf(mx, v);
        mn = fminf(mn, v);
    }
    for (int o = 32; o; o >>= 1) {
        mx = fmaxf(mx, __shfl_down(mx, o));
        mn = fminf(mn, __shfl_down(mn, o));
    }
    if (lane == 0) { rowmax[r] = mx; rowmin[r] = mn; }
}

// ---------------- gold-path score: unary + binary ----------------
__global__ __launch_bounds__(64) void score_kernel(const float* __restrict__ pot,
                                                   const float* __restrict__ trans,
                                                   const int* __restrict__ tags,
                                                   const int* __restrict__ seq_len,
                                                   float* __restrict__ scoreArr)
{
    int b = blockIdx.x;
    int lane = threadIdx.x;
    int L = seq_len[b];
    float s = 0.f;
    for (int t = lane; t < CRF_T; t += 64) {
        if (t < L) {
            int tg = tags[b * CRF_T + t];
            s += pot[((size_t)b * CRF_T + t) * CRF_K + tg];
            if (t >= 1) {
                int tp = tags[b * CRF_T + t - 1];
                s += trans[tp * CRF_K + tg];
            }
        }
    }
    for (int o = 32; o; o >>= 1) s += __shfl_down(s, o);
    if (lane == 0) scoreArr[b] = s;
}

#define E_IDS(X) X(0) X(1) X(2) X(3) X(4) X(5) X(6) X(7) X(8) X(9) X(10) X(11) \
                 X(12) X(13) X(14) X(15) X(16) X(17) X(18) X(19) X(20) X(21) X(22) X(23)
#define DECL_E(c) uint4 E##c;
#define LOAD_E(c) E##c = make_uint4(ecol[(4*(c)+0)*CRF_K], ecol[(4*(c)+1)*CRF_K], \
                                    ecol[(4*(c)+2)*CRF_K], ecol[(4*(c)+3)*CRF_K]);
#define DOT_E(c) { \
    uint4 a0 = *(const uint4*)&sAq[cur][0][4*(c)]; \
    uint4 a1 = *(const uint4*)&sAq[cur][1][4*(c)]; \
    Sa0 = DOT4(a0.x, E##c.x, Sa0); Sb0 = DOT4(a0.y, E##c.y, Sb0); \
    Sa0 = DOT4(a0.z, E##c.z, Sa0); Sb0 = DOT4(a0.w, E##c.w, Sb0); \
    Sa1 = DOT4(a1.x, E##c.x, Sa1); Sb1 = DOT4(a1.y, E##c.y, Sb1); \
    Sa1 = DOT4(a1.z, E##c.z, Sa1); Sb1 = DOT4(a1.w, E##c.w, Sb1); }

// ---------------- fused forward ----------------
// blocks 0..127   : Viterbi, 1 row/block, exact pruned max-plus (bit-exact f32), 2 barriers/step
// blocks 128..191 : lognorm, 2 rows/block; int8 E: 96 qwords in NAMED uint4 regs (no alloca ->
//                   no scratch) + 56 qwords in dynamic LDS. Zero per-step global E traffic.
// __launch_bounds__(640,2): VGPR cap 256 (need ~160). Dyn-LDS 134.4KB also forces 1 block/CU.
__global__ __launch_bounds__(FWD_NT, 2) void fwd_kernel(
    const float* __restrict__ pot,
    const float* __restrict__ trans,
    const uint32_t* __restrict__ EqT,
    const float* __restrict__ rowmax,
    const float* __restrict__ rowmin,
    const int* __restrict__ seq_len,
    uint16_t* __restrict__ bp,
    float* __restrict__ lognormArr,
    int* __restrict__ lastArr)
{
    extern __shared__ uint32_t eLds[];               // [QSTR][CRF_K] qwords 96..151
    const int bid = blockIdx.x;
    const int tid = threadIdx.x;
    const int lane = tid & 63, wid = tid >> 6;
    const bool act = tid < CRF_K;

    __shared__ __align__(16) float sAv[2][CRF_K];        // viterbi alpha dbuf
    __shared__ int sCand[FWD_NT];                        // per-wave candidate lists
    __shared__ int sRedI[NWAVE];
    __shared__ __align__(16) uint32_t sAq[2][2][QW];     // lognorm int8 alpha dbuf [buf][row][qword]
    __shared__ float sRedA[NWAVE], sRedB[NWAVE];
    __shared__ unsigned vSlot[2];                        // viterbi LB slots (parity)
    __shared__ unsigned lSlot[2][2];                     // lognorm max slots [row][parity]
    __shared__ float sB0f, sB1f;
    __shared__ int sRedC[NWAVE];

    if (bid < CRF_B) {
        // ================= Viterbi role =================
        const int b = bid;
        const int L = seq_len[b];
        const float* pb = pot + (size_t)b * CRF_T * CRF_K;
        float rmx = act ? rowmax[tid] : 0.f;
        float rmn = act ? rowmin[tid] : 0.f;
        if (act) sAv[0][tid] = pb[tid];
        if (tid == 0) { vSlot[0] = 0u; vSlot[1] = 0u; }
        int cur = 0;
        __syncthreads();

        for (int t = 1; t < L; ++t) {
            float a_own = act ? sAv[cur][tid] : -INFINITY;
            // LB = max_i (alpha_i + rowmin_i) via wave-shfl + LDS atomicMax (monotone key)
            float li = act ? a_own + rmn : -INFINITY;
            for (int o = 32; o; o >>= 1) li = fmaxf(li, __shfl_down(li, o));
            if (lane == 0) atomicMax(&vSlot[t & 1], fmono(li));
            __syncthreads();                             // B1
            const float LB = funmono(vSlot[t & 1]);
            if (tid == 0) vSlot[(t + 1) & 1] = 0u;       // reset other parity (ordered by B2)
            // candidates: alpha_i + rowmax_i >= LB  (provable superset of winners incl. ties)
            bool flag = act && (a_own + rmx >= LB);
            uint64_t mask = __ballot(flag);
            if (flag) sCand[(wid << 6) + __popcll(mask & ((1ull << lane) - 1ull))] = tid;
            if (lane == 0) sRedI[wid] = __popcll(mask);
            __syncthreads();                             // B2
            float emitv = act ? pb[(size_t)t * CRF_K + tid] : 0.f;
            if (act) {
                float v = -INFINITY; int ix = 0;
                #pragma unroll 2
                for (int w = 0; w < NWAVE; ++w) {
                    const int cw = sRedI[w];
                    const int base = w << 6;
                    for (int k0 = 0; k0 < cw; k0 += 4) {
                        #pragma unroll
                        for (int u = 0; u < 4; ++u) {
                            int kk = k0 + u;
                            int i = sCand[base + ((kk < cw) ? kk : 0)];  // dup-pad: earlier i, strict > no-op
                            float cnd = sAv[cur][i] + trans[i * CRF_K + tid];
                            if (cnd > v) { v = cnd; ix = i; }            // ascending i -> first-max
                        }
                    }
                }
                bp[((size_t)b * (CRF_T - 1) + (t - 1)) * CRF_K + tid] = (uint16_t)ix;
                sAv[cur ^ 1][tid] = v + emitv;
            }
            cur ^= 1;
        }

        // finalize: last = argmax_j alpha (first-max tie-break)
        float mv = act ? sAv[cur][tid] : -INFINITY;
        float y = mv;
        for (int o = 32; o; o >>= 1) y = fmaxf(y, __shfl_down(y, o));
        if (lane == 0) sRedA[wid] = y;
        __syncthreads();
        if (tid == 0) { float m = sRedA[0]; for (int w = 1; w < NWAVE; ++w) m = fmaxf(m, sRedA[w]); sB0f = m; }
        __syncthreads();
        float vmax = sB0f;
        int cand = (act && mv == vmax) ? tid : 0x7fffffff;
        for (int o = 32; o; o >>= 1) cand = min(cand, __shfl_down(cand, o));
        if (lane == 0) sRedC[wid] = cand;
        __syncthreads();
        if (tid == 0) {
            int mi = sRedC[0];
            for (int w = 1; w < NWAVE; ++w) mi = min(mi, sRedC[w]);
            lastArr[b] = mi;
        }
    } else {
        // ================= lognorm role (NB=2, int8 E in named regs + LDS) =================
        const int q = bid - CRF_B;
        const int b0 = 2 * q, b1 = b0 + 1;
        const int L0 = seq_len[b0], L1 = seq_len[b1];
        const int Tmax = max(L0, L1);
        const float* pb0 = pot + (size_t)b0 * CRF_T * CRF_K;
        const float* pb1 = pot + (size_t)b1 * CRF_T * CRF_K;

        // E prologue: 24 named uint4 (96 qwords) — SSA values, cannot hit scratch
        const uint32_t* ecol = EqT + tid;
        E_IDS(DECL_E)
        E_IDS(LOAD_E)
        // E qwords 96..151 -> dynamic LDS (includes zero pad 150,151 from prepE)
        for (int w = tid; w < QSTR * CRF_K; w += FWD_NT)
            eLds[w] = EqT[QREG * CRF_K + w];

        // init: m0 = max p0 per row; na = exp(p0 - m0) (max == 1 exactly)
        float p00 = act ? pb0[tid] : -INFINITY;
        float p01 = act ? pb1[tid] : -INFINITY;
        {
            float y0 = p00, y1 = p01;
            for (int o = 32; o; o >>= 1) { y0 = fmaxf(y0, __shfl_down(y0, o)); y1 = fmaxf(y1, __shfl_down(y1, o)); }
            if (lane == 0) { sRedA[wid] = y0; sRedB[wid] = y1; }
            __syncthreads();
            if (tid == 0) {
                float m0 = sRedA[0], m1 = sRedB[0];
                for (int w = 1; w < NWAVE; ++w) { m0 = fmaxf(m0, sRedA[w]); m1 = fmaxf(m1, sRedB[w]); }
                sB0f = m0; sB1f = m1;
            }
            __syncthreads();
        }
        float ls0 = sB0f, ls1 = sB1f;           // per-thread copies, kept identical
        float lsf0 = ls0, lsf1 = ls1;
        float afin0 = 0.f, afin1 = 0.f;
        if (act) {
            float na0 = __expf(p00 - sB0f);
            float na1 = __expf(p01 - sB1f);
            uint8_t* d0 = (uint8_t*)&sAq[0][0][0];
            uint8_t* d1 = (uint8_t*)&sAq[0][1][0];
            d0[tid] = (uint8_t)__float2int_rn(127.0f * na0);   // max na == 1 exactly
            d1[tid] = (uint8_t)__float2int_rn(127.0f * na1);
        }
        if (tid < 8) {   // zero pad bytes (qwords 150,151) of both rows, buf 0
            ((uint8_t*)&sAq[0][0][150])[tid & 7] = 0;
            ((uint8_t*)&sAq[0][1][150])[tid & 7] = 0;
        }
        if (tid >= 632) {  // zero pad of buf 1 (written once; frozen-copy preserves)
            ((uint8_t*)&sAq[1][0][150])[tid - 632] = 0;
            ((uint8_t*)&sAq[1][1][150])[tid - 632] = 0;
        }
        if (tid == 0) { lSlot[0][0] = 0u; lSlot[0][1] = 0u; lSlot[1][0] = 0u; lSlot[1][1] = 0u; }
        int cur = 0;
        __syncthreads();

        for (int t = 1; t < Tmax; ++t) {
            const bool lv0 = t < L0, lv1 = t < L1;
            float na0v = 0.f, na1v = 0.f;
            if (act) {
                int Sa0 = 0, Sb0 = 0, Sa1 = 0, Sb1 = 0;
                E_IDS(DOT_E)                             // 24 chunks, E from registers
                const uint32_t* ecl = eLds + tid;
                #pragma unroll
                for (int s = 0; s < QSTR / 4; ++s) {     // 14 chunks, E from LDS
                    uint32_t e0 = ecl[(4 * s + 0) * CRF_K];
                    uint32_t e1 = ecl[(4 * s + 1) * CRF_K];
                    uint32_t e2 = ecl[(4 * s + 2) * CRF_K];
                    uint32_t e3 = ecl[(4 * s + 3) * CRF_K];
                    uint4 a0 = *(const uint4*)&sAq[cur][0][QREG + 4 * s];
                    uint4 a1 = *(const uint4*)&sAq[cur][1][QREG + 4 * s];
                    Sa0 = DOT4(a0.x, e0, Sa0); Sb0 = DOT4(a0.y, e1, Sb0);
                    Sa0 = DOT4(a0.z, e2, Sa0); Sb0 = DOT4(a0.w, e3, Sb0);
                    Sa1 = DOT4(a1.x, e0, Sa1); Sb1 = DOT4(a1.y, e1, Sb1);
                    Sa1 = DOT4(a1.z, e2, Sa1); Sb1 = DOT4(a1.w, e3, Sb1);
                }
                int S0 = Sa0 + Sb0, S1 = Sa1 + Sb1;
                if (lv0) na0v = (float)S0 * INV7620 * __expf(pb0[(size_t)t * CRF_K + tid]);
                if (lv1) na1v = (float)S1 * INV7620 * __expf(pb1[(size_t)t * CRF_K + tid]);
                if (t == L0 - 1) { afin0 = na0v; lsf0 = ls0; }
                if (t == L1 - 1) { afin1 = na1v; lsf1 = ls1; }
            }
            // block max per row: wave shfl + LDS atomicMax (na >= 0 -> raw float bits monotone)
            float m0r = na0v, m1r = na1v;
            for (int o = 32; o; o >>= 1) { m0r = fmaxf(m0r, __shfl_down(m0r, o)); m1r = fmaxf(m1r, __shfl_down(m1r, o)); }
            if (lane == 0) {
                atomicMax(&lSlot[0][t & 1], __float_as_uint(m0r));
                atomicMax(&lSlot[1][t & 1], __float_as_uint(m1r));
            }
            __syncthreads();                                  // B1
            float m0 = __uint_as_float(lSlot[0][t & 1]);
            float m1 = __uint_as_float(lSlot[1][t & 1]);
            if (tid == 0) { lSlot[0][(t + 1) & 1] = 0u; lSlot[1][(t + 1) & 1] = 0u; }
            if (act) {
                uint8_t* d0 = (uint8_t*)&sAq[cur ^ 1][0][0];
                uint8_t* d1 = (uint8_t*)&sAq[cur ^ 1][1][0];
                const uint8_t* s0 = (const uint8_t*)&sAq[cur][0][0];
                const uint8_t* s1 = (const uint8_t*)&sAq[cur][1][0];
                if (lv0) { ls0 += __logf(m0); d0[tid] = (uint8_t)__float2int_rn(na0v * (127.0f / m0)); }
                else     { d0[tid] = s0[tid]; }
                if (lv1) { ls1 += __logf(m1); d1[tid] = (uint8_t)__float2int_rn(na1v * (127.0f / m1)); }
                else     { d1[tid] = s1[tid]; }
            }
            __syncthreads();                                  // B2
            cur ^= 1;
        }

        // finalize: lognorm_p = lsf_p + log(sum_j afin_p)
        float a0s = afin0, a1s = afin1;
        for (int o = 32; o; o >>= 1) { a0s += __shfl_down(a0s, o); a1s += __shfl_down(a1s, o); }
        if (lane == 0) { sRedA[wid] = a0s; sRedB[wid] = a1s; }
        __syncthreads();
        if (tid == 0) {
            float S0 = 0.f, S1 = 0.f;
            for (int w = 0; w < NWAVE; ++w) { S0 += sRedA[w]; S1 += sRedB[w]; }
            lognormArr[b0] = lsf0 + __logf(S0);
            lognormArr[b1] = lsf1 + __logf(S1);
        }
    }
}

// ---------------- backtrace ----------------
__global__ __launch_bounds__(64) void backtrace_kernel(const uint16_t* __restrict__ bp,
                                                       const int* __restrict__ seq_len,
                                                       const int* __restrict__ lastArr,
                                                       float* __restrict__ out)
{
    int r = blockIdx.x * 64 + threadIdx.x;
    if (r >= CRF_B) return;
    int L = seq_len[r];
    float* o = out + 1 + (size_t)r * CRF_T;
    int tag = lastArr[r];
    for (int t = CRF_T - 1; t >= L; --t) o[t] = 0.f;
    o[L - 1] = (float)tag;
    for (int t = L - 2; t >= 0; --t) {
        tag = bp[((size_t)r * (CRF_T - 1) + t) * CRF_K + tag];
        o[t] = (float)tag;
    }
}

// ---------------- loss = -mean(score - lognorm) ----------------
__global__ __launch_bounds__(128) void loss_kernel(const float* __restrict__ scoreArr,
                                                   const float* __restrict__ lognormArr,
                                                   float* __restrict__ out)
{
    int tid = threadIdx.x;
    float x = scoreArr[tid] - lognormArr[tid];
    for (int o = 32; o; o >>= 1) x += __shfl_down(x, o);
    __shared__ float r2[2];
    if ((tid & 63) == 0) r2[tid >> 6] = x;
    __syncthreads();
    if (tid == 0) out[0] = -(r2[0] + r2[1]) / (float)CRF_B;
}

extern "C" void kernel_launch(void* const* d_in, const int* in_sizes, int n_in,
                              void* d_out, int out_size, void* d_ws, size_t ws_size,
                              hipStream_t stream)
{
    const float* pot     = (const float*)d_in[0];
    const float* trans   = (const float*)d_in[1];
    const int*   tags    = (const int*)d_in[2];
    const int*   seq_len = (const int*)d_in[3];
    float* out = (float*)d_out;

    char* ws = (char*)d_ws;
    const size_t bpBytes  = (size_t)CRF_B * (CRF_T - 1) * CRF_K * 2;    // 39,168,000
    const size_t eqBytes  = (size_t)QW * CRF_K * 4;                     //    364,800
    uint16_t* bp     = (uint16_t*)ws;
    uint32_t* EqT    = (uint32_t*)(ws + bpBytes);
    float*    rowmax = (float*)(ws + bpBytes + eqBytes);
    float*    rowmin = rowmax + CRF_K;
    float* scoreArr   = rowmin + CRF_K;
    float* lognormArr = scoreArr + CRF_B;
    int*   lastArr    = (int*)(lognormArr + CRF_B);

    prepE_kernel<<<(QW * CRF_K + 255) / 256, 256, 0, stream>>>(trans, EqT);
    prep2_kernel<<<CRF_K, 64, 0, stream>>>(trans, rowmax, rowmin);
    score_kernel<<<CRF_B, 64, 0, stream>>>(pot, trans, tags, seq_len, scoreArr);
    fwd_kernel<<<CRF_B + CRF_B / 2, FWD_NT, QSTR * CRF_K * 4, stream>>>(
        pot, trans, EqT, rowmax, rowmin, seq_len, bp, lognormArr, lastArr);
    backtrace_kernel<<<(CRF_B + 63) / 64, 64, 0, stream>>>(bp, seq_len, lastArr, out);
    loss_kernel<<<1, 128, 0, stream>>>(scoreArr, lognormArr, out);
}

// Round 11
// 1918.505 us; speedup vs baseline: 8.2371x; 3.3556x over previous
//
#include <hip/hip_runtime.h>
#include <stdint.h>

#define CRF_B 128
#define CRF_T 256
#define CRF_K 600
#define FWD_NT 640          // 10 waves
#define NWAVE 10
#define QW 152              // packed quad-words per column (600/4 = 150, +2 zero pad)
#define QG 96               // qwords streamed from L2 each step (coalesced dword loads)
#define QSTR (QW - QG)      // 56 qwords cached in dynamic LDS (loaded once)
#define ESC 60.0f           // E int8 scale: byte = rn(60*exp(trans)) <= 127 for trans <= 0.75
#define INV7620 (1.0f/7620.0f)  // 1/(127*60)

#if __has_builtin(__builtin_amdgcn_sdot4)
#define DOT4(a,b,c) __builtin_amdgcn_sdot4((int)(a),(int)(b),(int)(c),false)
#else
__device__ __forceinline__ int DOT4(uint32_t a, uint32_t b, int c) {
    c += (int)(int8_t)(a)       * (int)(int8_t)(b);
    c += (int)(int8_t)(a >> 8)  * (int)(int8_t)(b >> 8);
    c += (int)(int8_t)(a >> 16) * (int)(int8_t)(b >> 16);
    c += (int)(int8_t)(a >> 24) * (int)(int8_t)(b >> 24);
    return c;
}
#endif

// order-preserving float<->uint for atomicMax-based reductions
__device__ __forceinline__ uint32_t fmono(float x) {
    uint32_t k = __float_as_uint(x);
    return (k & 0x80000000u) ? ~k : (k | 0x80000000u);
}
__device__ __forceinline__ float funmono(uint32_t k) {
    return __uint_as_float((k & 0x80000000u) ? (k ^ 0x80000000u) : ~k);
}

// ---------------- prepE: EqT[q][j] word = int8x4 of rn(ESC*exp(trans[4q+k][j])) ----------------
__global__ __launch_bounds__(256) void prepE_kernel(const float* __restrict__ trans,
                                                    uint32_t* __restrict__ EqT)
{
    int idx = blockIdx.x * 256 + threadIdx.x;       // q*600 + j
    if (idx < QW * CRF_K) {
        int q = idx / CRF_K, j = idx % CRF_K;
        uint32_t w = 0;
        #pragma unroll
        for (int k = 0; k < 4; ++k) {
            int i = 4 * q + k;
            int b = 0;
            if (i < CRF_K) {
                b = __float2int_rn(ESC * __expf(trans[i * CRF_K + j]));
                b = min(127, max(0, b));
            }
            w |= ((uint32_t)(b & 0xff)) << (8 * k);
        }
        EqT[idx] = w;
    }
}

// ---------------- prep2: per-row max/min of trans (viterbi pruning bounds) ----------------
__global__ __launch_bounds__(64) void prep2_kernel(const float* __restrict__ trans,
                                                   float* __restrict__ rowmax,
                                                   float* __restrict__ rowmin)
{
    int r = blockIdx.x;
    int lane = threadIdx.x;
    float mx = -INFINITY, mn = INFINITY;
    for (int j = lane; j < CRF_K; j += 64) {
        float v = trans[r * CRF_K + j];
        mx = fmaxf(mx, v);
        mn = fminf(mn, v);
    }
    for (int o = 32; o; o >>= 1) {
        mx = fmaxf(mx, __shfl_down(mx, o));
        mn = fminf(mn, __shfl_down(mn, o));
    }
    if (lane == 0) { rowmax[r] = mx; rowmin[r] = mn; }
}

// ---------------- gold-path score: unary + binary ----------------
__global__ __launch_bounds__(64) void score_kernel(const float* __restrict__ pot,
                                                   const float* __restrict__ trans,
                                                   const int* __restrict__ tags,
                                                   const int* __restrict__ seq_len,
                                                   float* __restrict__ scoreArr)
{
    int b = blockIdx.x;
    int lane = threadIdx.x;
    int L = seq_len[b];
    float s = 0.f;
    for (int t = lane; t < CRF_T; t += 64) {
        if (t < L) {
            int tg = tags[b * CRF_T + t];
            s += pot[((size_t)b * CRF_T + t) * CRF_K + tg];
            if (t >= 1) {
                int tp = tags[b * CRF_T + t - 1];
                s += trans[tp * CRF_K + tg];
            }
        }
    }
    for (int o = 32; o; o >>= 1) s += __shfl_down(s, o);
    if (lane == 0) scoreArr[b] = s;
}

// ---------------- fused forward ----------------
// blocks 0..127   : Viterbi, 1 row/block, exact pruned max-plus (bit-exact f32), 2 barriers/step
// blocks 128..191 : lognorm, 2 rows/block; int8 E: 56 qword-rows in dynamic LDS (loaded once)
//                   + 96 qword-rows streamed from L2 each step (coalesced dword loads).
//                   NO per-thread E array/registers -> nothing for the RA to spill.
__global__ __launch_bounds__(FWD_NT, 2) void fwd_kernel(
    const float* __restrict__ pot,
    const float* __restrict__ trans,
    const uint32_t* __restrict__ EqT,
    const float* __restrict__ rowmax,
    const float* __restrict__ rowmin,
    const int* __restrict__ seq_len,
    uint16_t* __restrict__ bp,
    float* __restrict__ lognormArr,
    int* __restrict__ lastArr)
{
    extern __shared__ uint32_t eLds[];               // [QSTR][CRF_K] qwords QG..151
    const int bid = blockIdx.x;
    const int tid = threadIdx.x;
    const int lane = tid & 63, wid = tid >> 6;
    const bool act = tid < CRF_K;

    __shared__ __align__(16) float sAv[2][CRF_K];        // viterbi alpha dbuf
    __shared__ int sCand[FWD_NT];                        // per-wave candidate lists
    __shared__ int sRedI[NWAVE];
    __shared__ __align__(16) uint32_t sAq[2][2][QW];     // lognorm int8 alpha dbuf [buf][row][qword]
    __shared__ float sRedA[NWAVE], sRedB[NWAVE];
    __shared__ unsigned vSlot[2];                        // viterbi LB slots (parity)
    __shared__ unsigned lSlot[2][2];                     // lognorm max slots [row][parity]
    __shared__ float sB0f, sB1f;
    __shared__ int sRedC[NWAVE];

    if (bid < CRF_B) {
        // ================= Viterbi role =================
        const int b = bid;
        const int L = seq_len[b];
        const float* pb = pot + (size_t)b * CRF_T * CRF_K;
        float rmx = act ? rowmax[tid] : 0.f;
        float rmn = act ? rowmin[tid] : 0.f;
        if (act) sAv[0][tid] = pb[tid];
        if (tid == 0) { vSlot[0] = 0u; vSlot[1] = 0u; }
        int cur = 0;
        __syncthreads();

        for (int t = 1; t < L; ++t) {
            float a_own = act ? sAv[cur][tid] : -INFINITY;
            // LB = max_i (alpha_i + rowmin_i) via wave-shfl + LDS atomicMax (monotone key)
            float li = act ? a_own + rmn : -INFINITY;
            for (int o = 32; o; o >>= 1) li = fmaxf(li, __shfl_down(li, o));
            if (lane == 0) atomicMax(&vSlot[t & 1], fmono(li));
            __syncthreads();                             // B1
            const float LB = funmono(vSlot[t & 1]);
            if (tid == 0) vSlot[(t + 1) & 1] = 0u;       // reset other parity (ordered by B2)
            // candidates: alpha_i + rowmax_i >= LB  (provable superset of winners incl. ties)
            bool flag = act && (a_own + rmx >= LB);
            uint64_t mask = __ballot(flag);
            if (flag) sCand[(wid << 6) + __popcll(mask & ((1ull << lane) - 1ull))] = tid;
            if (lane == 0) sRedI[wid] = __popcll(mask);
            __syncthreads();                             // B2
            float emitv = act ? pb[(size_t)t * CRF_K + tid] : 0.f;
            if (act) {
                float v = -INFINITY; int ix = 0;
                #pragma unroll 2
                for (int w = 0; w < NWAVE; ++w) {
                    const int cw = sRedI[w];
                    const int base = w << 6;
                    for (int k0 = 0; k0 < cw; k0 += 4) {
                        #pragma unroll
                        for (int u = 0; u < 4; ++u) {
                            int kk = k0 + u;
                            int i = sCand[base + ((kk < cw) ? kk : 0)];  // dup-pad: earlier i, strict > no-op
                            float cnd = sAv[cur][i] + trans[i * CRF_K + tid];
                            if (cnd > v) { v = cnd; ix = i; }            // ascending i -> first-max
                        }
                    }
                }
                bp[((size_t)b * (CRF_T - 1) + (t - 1)) * CRF_K + tid] = (uint16_t)ix;
                sAv[cur ^ 1][tid] = v + emitv;
            }
            cur ^= 1;
        }

        // finalize: last = argmax_j alpha (first-max tie-break)
        float mv = act ? sAv[cur][tid] : -INFINITY;
        float y = mv;
        for (int o = 32; o; o >>= 1) y = fmaxf(y, __shfl_down(y, o));
        if (lane == 0) sRedA[wid] = y;
        __syncthreads();
        if (tid == 0) { float m = sRedA[0]; for (int w = 1; w < NWAVE; ++w) m = fmaxf(m, sRedA[w]); sB0f = m; }
        __syncthreads();
        float vmax = sB0f;
        int cand = (act && mv == vmax) ? tid : 0x7fffffff;
        for (int o = 32; o; o >>= 1) cand = min(cand, __shfl_down(cand, o));
        if (lane == 0) sRedC[wid] = cand;
        __syncthreads();
        if (tid == 0) {
            int mi = sRedC[0];
            for (int w = 1; w < NWAVE; ++w) mi = min(mi, sRedC[w]);
            lastArr[b] = mi;
        }
    } else {
        // ================= lognorm role (NB=2, int8 E: LDS cache + L2 stream) =================
        const int q = bid - CRF_B;
        const int b0 = 2 * q, b1 = b0 + 1;
        const int L0 = seq_len[b0], L1 = seq_len[b1];
        const int Tmax = max(L0, L1);
        const float* pb0 = pot + (size_t)b0 * CRF_T * CRF_K;
        const float* pb1 = pot + (size_t)b1 * CRF_T * CRF_K;

        // E qwords QG..151 -> dynamic LDS (includes zero pad 150,151 from prepE), loaded once
        for (int w = tid; w < QSTR * CRF_K; w += FWD_NT)
            eLds[w] = EqT[QG * CRF_K + w];

        // init: m0 = max p0 per row; na = exp(p0 - m0) (max == 1 exactly)
        float p00 = act ? pb0[tid] : -INFINITY;
        float p01 = act ? pb1[tid] : -INFINITY;
        {
            float y0 = p00, y1 = p01;
            for (int o = 32; o; o >>= 1) { y0 = fmaxf(y0, __shfl_down(y0, o)); y1 = fmaxf(y1, __shfl_down(y1, o)); }
            if (lane == 0) { sRedA[wid] = y0; sRedB[wid] = y1; }
            __syncthreads();
            if (tid == 0) {
                float m0 = sRedA[0], m1 = sRedB[0];
                for (int w = 1; w < NWAVE; ++w) { m0 = fmaxf(m0, sRedA[w]); m1 = fmaxf(m1, sRedB[w]); }
                sB0f = m0; sB1f = m1;
            }
            __syncthreads();
        }
        float ls0 = sB0f, ls1 = sB1f;           // per-thread copies, kept identical
        float lsf0 = ls0, lsf1 = ls1;
        float afin0 = 0.f, afin1 = 0.f;
        if (act) {
            float na0 = __expf(p00 - sB0f);
            float na1 = __expf(p01 - sB1f);
            uint8_t* d0 = (uint8_t*)&sAq[0][0][0];
            uint8_t* d1 = (uint8_t*)&sAq[0][1][0];
            d0[tid] = (uint8_t)__float2int_rn(127.0f * na0);   // max na == 1 exactly
            d1[tid] = (uint8_t)__float2int_rn(127.0f * na1);
        }
        if (tid < 8) {   // zero pad bytes (qwords 150,151) of both rows, buf 0
            ((uint8_t*)&sAq[0][0][150])[tid & 7] = 0;
            ((uint8_t*)&sAq[0][1][150])[tid & 7] = 0;
        }
        if (tid >= 632) {  // zero pad of buf 1 (written once; frozen-copy preserves)
            ((uint8_t*)&sAq[1][0][150])[tid - 632] = 0;
            ((uint8_t*)&sAq[1][1][150])[tid - 632] = 0;
        }
        if (tid == 0) { lSlot[0][0] = 0u; lSlot[0][1] = 0u; lSlot[1][0] = 0u; lSlot[1][1] = 0u; }
        int cur = 0;
        __syncthreads();

        for (int t = 1; t < Tmax; ++t) {
            const bool lv0 = t < L0, lv1 = t < L1;
            float na0v = 0.f, na1v = 0.f;
            if (act) {
                int Sa0 = 0, Sb0 = 0, Sa1 = 0, Sb1 = 0;
                const uint32_t* eg = EqT + tid;          // coalesced: lane j reads word q*600+j
                #pragma unroll 6
                for (int c = 0; c < QG / 4; ++c) {       // 24 chunks, E streamed from L2
                    uint32_t e0 = eg[(4 * c + 0) * CRF_K];
                    uint32_t e1 = eg[(4 * c + 1) * CRF_K];
                    uint32_t e2 = eg[(4 * c + 2) * CRF_K];
                    uint32_t e3 = eg[(4 * c + 3) * CRF_K];
                    uint4 a0 = *(const uint4*)&sAq[cur][0][4 * c];
                    uint4 a1 = *(const uint4*)&sAq[cur][1][4 * c];
                    Sa0 = DOT4(a0.x, e0, Sa0); Sb0 = DOT4(a0.y, e1, Sb0);
                    Sa0 = DOT4(a0.z, e2, Sa0); Sb0 = DOT4(a0.w, e3, Sb0);
                    Sa1 = DOT4(a1.x, e0, Sa1); Sb1 = DOT4(a1.y, e1, Sb1);
                    Sa1 = DOT4(a1.z, e2, Sa1); Sb1 = DOT4(a1.w, e3, Sb1);
                }
                const uint32_t* ecl = eLds + tid;
                #pragma unroll
                for (int s = 0; s < QSTR / 4; ++s) {     // 14 chunks, E from LDS
                    uint32_t e0 = ecl[(4 * s + 0) * CRF_K];
                    uint32_t e1 = ecl[(4 * s + 1) * CRF_K];
                    uint32_t e2 = ecl[(4 * s + 2) * CRF_K];
                    uint32_t e3 = ecl[(4 * s + 3) * CRF_K];
                    uint4 a0 = *(const uint4*)&sAq[cur][0][QG + 4 * s];
                    uint4 a1 = *(const uint4*)&sAq[cur][1][QG + 4 * s];
                    Sa0 = DOT4(a0.x, e0, Sa0); Sb0 = DOT4(a0.y, e1, Sb0);
                    Sa0 = DOT4(a0.z, e2, Sa0); Sb0 = DOT4(a0.w, e3, Sb0);
                    Sa1 = DOT4(a1.x, e0, Sa1); Sb1 = DOT4(a1.y, e1, Sb1);
                    Sa1 = DOT4(a1.z, e2, Sa1); Sb1 = DOT4(a1.w, e3, Sb1);
                }
                int S0 = Sa0 + Sb0, S1 = Sa1 + Sb1;
                if (lv0) na0v = (float)S0 * INV7620 * __expf(pb0[(size_t)t * CRF_K + tid]);
                if (lv1) na1v = (float)S1 * INV7620 * __expf(pb1[(size_t)t * CRF_K + tid]);
                if (t == L0 - 1) { afin0 = na0v; lsf0 = ls0; }
                if (t == L1 - 1) { afin1 = na1v; lsf1 = ls1; }
            }
            // block max per row: wave shfl + LDS atomicMax (na >= 0 -> raw float bits monotone)
            float m0r = na0v, m1r = na1v;
            for (int o = 32; o; o >>= 1) { m0r = fmaxf(m0r, __shfl_down(m0r, o)); m1r = fmaxf(m1r, __shfl_down(m1r, o)); }
            if (lane == 0) {
                atomicMax(&lSlot[0][t & 1], __float_as_uint(m0r));
                atomicMax(&lSlot[1][t & 1], __float_as_uint(m1r));
            }
            __syncthreads();                                  // B1
            float m0 = __uint_as_float(lSlot[0][t & 1]);
            float m1 = __uint_as_float(lSlot[1][t & 1]);
            if (tid == 0) { lSlot[0][(t + 1) & 1] = 0u; lSlot[1][(t + 1) & 1] = 0u; }
            if (act) {
                uint8_t* d0 = (uint8_t*)&sAq[cur ^ 1][0][0];
                uint8_t* d1 = (uint8_t*)&sAq[cur ^ 1][1][0];
                const uint8_t* s0 = (const uint8_t*)&sAq[cur][0][0];
                const uint8_t* s1 = (const uint8_t*)&sAq[cur][1][0];
                if (lv0) { ls0 += __logf(m0); d0[tid] = (uint8_t)__float2int_rn(na0v * (127.0f / m0)); }
                else     { d0[tid] = s0[tid]; }
                if (lv1) { ls1 += __logf(m1); d1[tid] = (uint8_t)__float2int_rn(na1v * (127.0f / m1)); }
                else     { d1[tid] = s1[tid]; }
            }
            __syncthreads();                                  // B2
            cur ^= 1;
        }

        // finalize: lognorm_p = lsf_p + log(sum_j afin_p)
        float a0s = afin0, a1s = afin1;
        for (int o = 32; o; o >>= 1) { a0s += __shfl_down(a0s, o); a1s += __shfl_down(a1s, o); }
        if (lane == 0) { sRedA[wid] = a0s; sRedB[wid] = a1s; }
        __syncthreads();
        if (tid == 0) {
            float S0 = 0.f, S1 = 0.f;
            for (int w = 0; w < NWAVE; ++w) { S0 += sRedA[w]; S1 += sRedB[w]; }
            lognormArr[b0] = lsf0 + __logf(S0);
            lognormArr[b1] = lsf1 + __logf(S1);
        }
    }
}

// ---------------- backtrace ----------------
__global__ __launch_bounds__(64) void backtrace_kernel(const uint16_t* __restrict__ bp,
                                                       const int* __restrict__ seq_len,
                                                       const int* __restrict__ lastArr,
                                                       float* __restrict__ out)
{
    int r = blockIdx.x * 64 + threadIdx.x;
    if (r >= CRF_B) return;
    int L = seq_len[r];
    float* o = out + 1 + (size_t)r * CRF_T;
    int tag = lastArr[r];
    for (int t = CRF_T - 1; t >= L; --t) o[t] = 0.f;
    o[L - 1] = (float)tag;
    for (int t = L - 2; t >= 0; --t) {
        tag = bp[((size_t)r * (CRF_T - 1) + t) * CRF_K + tag];
        o[t] = (float)tag;
    }
}

// ---------------- loss = -mean(score - lognorm) ----------------
__global__ __launch_bounds__(128) void loss_kernel(const float* __restrict__ scoreArr,
                                                   const float* __restrict__ lognormArr,
                                                   float* __restrict__ out)
{
    int tid = threadIdx.x;
    float x = scoreArr[tid] - lognormArr[tid];
    for (int o = 32; o; o >>= 1) x += __shfl_down(x, o);
    __shared__ float r2[2];
    if ((tid & 63) == 0) r2[tid >> 6] = x;
    __syncthreads();
    if (tid == 0) out[0] = -(r2[0] + r2[1]) / (float)CRF_B;
}

extern "C" void kernel_launch(void* const* d_in, const int* in_sizes, int n_in,
                              void* d_out, int out_size, void* d_ws, size_t ws_size,
                              hipStream_t stream)
{
    const float* pot     = (const float*)d_in[0];
    const float* trans   = (const float*)d_in[1];
    const int*   tags    = (const int*)d_in[2];
    const int*   seq_len = (const int*)d_in[3];
    float* out = (float*)d_out;

    char* ws = (char*)d_ws;
    const size_t bpBytes  = (size_t)CRF_B * (CRF_T - 1) * CRF_K * 2;    // 39,168,000
    const size_t eqBytes  = (size_t)QW * CRF_K * 4;                     //    364,800
    uint16_t* bp     = (uint16_t*)ws;
    uint32_t* EqT    = (uint32_t*)(ws + bpBytes);
    float*    rowmax = (float*)(ws + bpBytes + eqBytes);
    float*    rowmin = rowmax + CRF_K;
    float* scoreArr   = rowmin + CRF_K;
    float* lognormArr = scoreArr + CRF_B;
    int*   lastArr    = (int*)(lognormArr + CRF_B);

    prepE_kernel<<<(QW * CRF_K + 255) / 256, 256, 0, stream>>>(trans, EqT);
    prep2_kernel<<<CRF_K, 64, 0, stream>>>(trans, rowmax, rowmin);
    score_kernel<<<CRF_B, 64, 0, stream>>>(pot, trans, tags, seq_len, scoreArr);
    fwd_kernel<<<CRF_B + CRF_B / 2, FWD_NT, QSTR * CRF_K * 4, stream>>>(
        pot, trans, EqT, rowmax, rowmin, seq_len, bp, lognormArr, lastArr);
    backtrace_kernel<<<(CRF_B + 63) / 64, 64, 0, stream>>>(bp, seq_len, lastArr, out);
    loss_kernel<<<1, 128, 0, stream>>>(scoreArr, lognormArr, out);
}